// Round 5
// baseline (21352.605 us; speedup 1.0000x reference)
//
#include <hip/hip_runtime.h>
#include <math.h>

#define B 64
#define S 32
#define NN 128
#define DV 512
#define DW 300
#define DH 1024
#define CLS 1024
#define T_CTRL 12
#define LL 4
#define NA 28
#define NE 16
#define MM 6
#define NB 512
#define NT 256

__device__ __forceinline__ float sigmoidf_(float x) { return 1.0f / (1.0f + expf(-x)); }

struct KP {
  const int* questions; const int* qlen;
  const float* conn; const int* cat_mat; const int* v_idx;
  const float* attr_emb; const float* edge_cat; const float* enc_emb;
  const float* Wx; const float* Wh; const float* b_lstm;
  const float* W_cq; const float* b_cq; const float* W_mod; const float* W_att;
  const float* W_q; const float* b_q; const float* W_find; const float* W_desc;
  const float* W_cls1; const float* b_cls1; const float* W_cls2; const float* b_cls2;
  float* outs; float* share; float* partE; float* partH; float* partL;
  float* c_ctrl; float* c_lstm; float* uwe; float* we; float* mp; float* spv;
  float* ain; float* aw4; float* afind; float* atr; float* asum;
  float* att_stack; float* sptr; float* mem; float* pooled;
  int* bar; float* logits;
};

// ---- grid barrier (agent scope). bar[0]=count, bar[32]=generation ----
__device__ __forceinline__ void gsync(int* bar) {
  __syncthreads();
  __threadfence();
  if (threadIdx.x == 0) {
    int* cnt = bar; int* gen = bar + 32;
    int g = __hip_atomic_load(gen, __ATOMIC_RELAXED, __HIP_MEMORY_SCOPE_AGENT);
    int prev = __hip_atomic_fetch_add(cnt, 1, __ATOMIC_ACQ_REL, __HIP_MEMORY_SCOPE_AGENT);
    if (prev == NB - 1) {
      __hip_atomic_store(cnt, 0, __ATOMIC_RELAXED, __HIP_MEMORY_SCOPE_AGENT);
      __hip_atomic_fetch_add(gen, 1, __ATOMIC_RELEASE, __HIP_MEMORY_SCOPE_AGENT);
    } else {
      while (__hip_atomic_load(gen, __ATOMIC_ACQUIRE, __HIP_MEMORY_SCOPE_AGENT) == g)
        __builtin_amdgcn_s_sleep(8);
    }
  }
  __syncthreads();
}

// ---- one 64x64-tile K-chunk GEMM job. Ast [32][65], Ws [32][64] in lds ----
template<class AF, class WF>
__device__ __forceinline__ void gemm_job(float* lds, int tile, int chunk, int Kc, int K,
                                         AF&& loadA, WF&& loadW, float* part, int Cld) {
  float* Ast = lds;
  float* Ws  = lds + 2080;
  const int tid = threadIdx.x;
  const int j0 = tile * 64;
  const int kbeg = chunk * Kc;
  const int kend = (kbeg + Kc < K) ? (kbeg + Kc) : K;
  const int rg = tid & 15, cg = tid >> 4;
  float acc[4][4] = {};
  for (int kt = kbeg; kt < kend; kt += 32) {
    #pragma unroll
    for (int i2 = 0; i2 < 2; ++i2) {
      int idx = tid + i2 * 256;
      int r = idx >> 3, k4 = (idx & 7) * 4;
      float4 av = loadA(r, kt + k4);
      Ast[(k4 + 0) * 65 + r] = av.x; Ast[(k4 + 1) * 65 + r] = av.y;
      Ast[(k4 + 2) * 65 + r] = av.z; Ast[(k4 + 3) * 65 + r] = av.w;
    }
    #pragma unroll
    for (int i2 = 0; i2 < 2; ++i2) {
      int idx = tid + i2 * 256;
      int kk = idx >> 4, j4 = (idx & 15) * 4;
      float4 wv = loadW(kt + kk, j0 + j4);
      *(float4*)&Ws[kk * 64 + j4] = wv;
    }
    __syncthreads();
    #pragma unroll
    for (int k = 0; k < 32; ++k) {
      float a0 = Ast[k*65+rg], a1 = Ast[k*65+rg+16], a2 = Ast[k*65+rg+32], a3 = Ast[k*65+rg+48];
      float4 w = *(const float4*)&Ws[k*64 + cg*4];
      acc[0][0]=fmaf(a0,w.x,acc[0][0]); acc[0][1]=fmaf(a0,w.y,acc[0][1]); acc[0][2]=fmaf(a0,w.z,acc[0][2]); acc[0][3]=fmaf(a0,w.w,acc[0][3]);
      acc[1][0]=fmaf(a1,w.x,acc[1][0]); acc[1][1]=fmaf(a1,w.y,acc[1][1]); acc[1][2]=fmaf(a1,w.z,acc[1][2]); acc[1][3]=fmaf(a1,w.w,acc[1][3]);
      acc[2][0]=fmaf(a2,w.x,acc[2][0]); acc[2][1]=fmaf(a2,w.y,acc[2][1]); acc[2][2]=fmaf(a2,w.z,acc[2][2]); acc[2][3]=fmaf(a2,w.w,acc[2][3]);
      acc[3][0]=fmaf(a3,w.x,acc[3][0]); acc[3][1]=fmaf(a3,w.y,acc[3][1]); acc[3][2]=fmaf(a3,w.z,acc[3][2]); acc[3][3]=fmaf(a3,w.w,acc[3][3]);
    }
    __syncthreads();
  }
  float* op = part + (size_t)chunk * 64 * Cld + j0 + cg * 4;
  #pragma unroll
  for (int m = 0; m < 4; ++m)
    *(float4*)&op[(size_t)(rg + 16 * m) * Cld] = make_float4(acc[m][0], acc[m][1], acc[m][2], acc[m][3]);
}

// ---- TRANSW variant: loadWT(j,k) returns float4 along k ----
template<class AF, class WF>
__device__ __forceinline__ void gemm_job_t(float* lds, int tile, int chunk, int Kc, int K,
                                           AF&& loadA, WF&& loadWT, float* part, int Cld) {
  float* Ast = lds;
  float* Ws  = lds + 2080;
  const int tid = threadIdx.x;
  const int j0 = tile * 64;
  const int kbeg = chunk * Kc;
  const int kend = (kbeg + Kc < K) ? (kbeg + Kc) : K;
  const int rg = tid & 15, cg = tid >> 4;
  float acc[4][4] = {};
  for (int kt = kbeg; kt < kend; kt += 32) {
    #pragma unroll
    for (int i2 = 0; i2 < 2; ++i2) {
      int idx = tid + i2 * 256;
      int r = idx >> 3, k4 = (idx & 7) * 4;
      float4 av = loadA(r, kt + k4);
      Ast[(k4 + 0) * 65 + r] = av.x; Ast[(k4 + 1) * 65 + r] = av.y;
      Ast[(k4 + 2) * 65 + r] = av.z; Ast[(k4 + 3) * 65 + r] = av.w;
    }
    #pragma unroll
    for (int i2 = 0; i2 < 2; ++i2) {
      int idx = tid + i2 * 256;
      int jloc = idx >> 3, k4 = (idx & 7) * 4;
      float4 wv = loadWT(j0 + jloc, kt + k4);
      Ws[(k4+0)*64 + jloc] = wv.x; Ws[(k4+1)*64 + jloc] = wv.y;
      Ws[(k4+2)*64 + jloc] = wv.z; Ws[(k4+3)*64 + jloc] = wv.w;
    }
    __syncthreads();
    #pragma unroll
    for (int k = 0; k < 32; ++k) {
      float a0 = Ast[k*65+rg], a1 = Ast[k*65+rg+16], a2 = Ast[k*65+rg+32], a3 = Ast[k*65+rg+48];
      float4 w = *(const float4*)&Ws[k*64 + cg*4];
      acc[0][0]=fmaf(a0,w.x,acc[0][0]); acc[0][1]=fmaf(a0,w.y,acc[0][1]); acc[0][2]=fmaf(a0,w.z,acc[0][2]); acc[0][3]=fmaf(a0,w.w,acc[0][3]);
      acc[1][0]=fmaf(a1,w.x,acc[1][0]); acc[1][1]=fmaf(a1,w.y,acc[1][1]); acc[1][2]=fmaf(a1,w.z,acc[1][2]); acc[1][3]=fmaf(a1,w.w,acc[1][3]);
      acc[2][0]=fmaf(a2,w.x,acc[2][0]); acc[2][1]=fmaf(a2,w.y,acc[2][1]); acc[2][2]=fmaf(a2,w.z,acc[2][2]); acc[2][3]=fmaf(a2,w.w,acc[2][3]);
      acc[3][0]=fmaf(a3,w.x,acc[3][0]); acc[3][1]=fmaf(a3,w.y,acc[3][1]); acc[3][2]=fmaf(a3,w.z,acc[3][2]); acc[3][3]=fmaf(a3,w.w,acc[3][3]);
    }
    __syncthreads();
  }
  float* op = part + (size_t)chunk * 64 * Cld + j0 + cg * 4;
  #pragma unroll
  for (int m = 0; m < 4; ++m)
    *(float4*)&op[(size_t)(rg + 16 * m) * Cld] = make_float4(acc[m][0], acc[m][1], acc[m][2], acc[m][3]);
}

__global__ __launch_bounds__(NT, 2) void mega_kernel(KP p) {
  __shared__ float lds[4160];
  const int tid = threadIdx.x;
  int* bar = p.bar;
  float* partLSTM = p.share;                 // [7][64][4096]
  float* partA = p.share;                    // [8][64][1024]
  float* partB = p.share + 524288;           // [16][64][1088]
  float* partC = p.share + 1638400;          // [16][64][512]
  float* partD = p.share + 2162688;          // [8][64][576]
  float* outs = p.outs;

  // =================== LSTM ===================
  for (int t = 0; t < S; ++t) {
    const int K = (t == 0) ? 320 : 1344;
    const int SKt = (t == 0) ? 2 : 7;
    const int njobs = 64 * SKt;
    auto Al = [&](int r, int k) -> float4 {
      if (k < 320) {
        if (k < 300) { int qid = p.questions[r * 32 + t];
                       return *(const float4*)&p.enc_emb[(size_t)qid * 300 + k]; }
        return make_float4(0.f, 0.f, 0.f, 0.f);
      }
      return *(const float4*)&outs[(size_t)(t - 1) * 65536 + r * 1024 + (k - 320)];
    };
    auto Wl = [&](int k, int j) -> float4 {
      if (k < 300) return *(const float4*)&p.Wx[(size_t)k * 4096 + j];
      if (k < 320) return make_float4(0.f, 0.f, 0.f, 0.f);
      return *(const float4*)&p.Wh[(size_t)(k - 320) * 4096 + j];
    };
    for (int job = blockIdx.x; job < njobs; job += NB)
      gemm_job(lds, job & 63, job >> 6, 192, K, Al, Wl, partLSTM, 4096);
    gsync(bar);
    // gates
    {
      int idx = blockIdx.x * NT + tid;
      if (idx < 65536) {
        int b = idx >> 10, j = idx & 1023;
        float gi = 0.f, gf = 0.f, gg = 0.f, go = 0.f;
        for (int c = 0; c < SKt; ++c) {
          const float* pp = partLSTM + (size_t)c * 262144 + b * 4096;
          gi += pp[j]; gf += pp[1024 + j]; gg += pp[2048 + j]; go += pp[3072 + j];
        }
        gi += p.b_lstm[j]; gf += p.b_lstm[1024 + j]; gg += p.b_lstm[2048 + j]; go += p.b_lstm[3072 + j];
        float cc = sigmoidf_(gf) * p.c_lstm[idx] + sigmoidf_(gi) * tanhf(gg);
        outs[(size_t)t * 65536 + idx] = sigmoidf_(go) * tanhf(cc);
        p.c_lstm[idx] = cc;
      }
    }
    gsync(bar);
  }

  // =================== control loop ===================
  for (int it = 0; it < T_CTRL; ++it) {
    // ---- C1: gemmA (cq partials) + redE of previous iter ----
    {
      auto Al = [&](int r, int k) -> float4 {
        if (k < 1024) return *(const float4*)&p.c_ctrl[r * 1024 + k];
        int tq = p.qlen[r] - 1;
        return *(const float4*)&outs[(size_t)tq * 65536 + r * 1024 + (k - 1024)];
      };
      auto Wl = [&](int k, int j) -> float4 {
        return *(const float4*)&p.W_cq[(size_t)k * 1024 + j];
      };
      int njobs = (it > 0) ? 256 : 128;
      for (int job = blockIdx.x; job < njobs; job += NB) {
        if (job < 128) {
          gemm_job(lds, job & 15, job >> 4, 256, 2048, Al, Wl, partA, 1024);
        } else {
          int idx = (job - 128) * 256 + tid;   // < 32768
          int b = idx >> 9, jj = idx & 511;
          const float* m = &p.mp[b * 6];
          float s04 = m[0] + m[1] + m[2] + m[3] + m[4];
          float s = 0.f;
          for (int c = 0; c < 8; ++c) s += p.partE[(size_t)c * 32768 + b * 512 + jj];
          p.mem[b * 512 + jj] = s04 * p.mem[b * 512 + jj] + m[5] * s;
          __syncthreads();
        }
      }
      gsync(bar);
    }
    // ---- C2: gemmB (am partials), A = tanh(red(partA)+b_cq) ----
    {
      auto Al = [&](int r, int k) -> float4 {
        float4 s = *(const float4*)&p.b_cq[k];
        for (int c = 0; c < 8; ++c) {
          float4 v = *(const float4*)&partA[(size_t)c * 65536 + r * 1024 + k];
          s.x += v.x; s.y += v.y; s.z += v.z; s.w += v.w;
        }
        return make_float4(tanhf(s.x), tanhf(s.y), tanhf(s.z), tanhf(s.w));
      };
      auto Wl = [&](int k, int j) -> float4 {
        if (j < 1024) return *(const float4*)&p.W_att[(size_t)k * 1024 + j];
        float v[4];
        #pragma unroll
        for (int i = 0; i < 4; ++i) {
          int jj = j + i;
          v[i] = (jj < 1030) ? p.W_mod[(size_t)k * 6 + (jj - 1024)] : 0.f;
        }
        return make_float4(v[0], v[1], v[2], v[3]);
      };
      for (int job = blockIdx.x; job < 272; job += NB)
        gemm_job(lds, job % 17, job / 17, 64, 1024, Al, Wl, partB, 1088);
      gsync(bar);
    }
    // ---- C3: attention (reduce attW, al, softmax, c_ctrl) ----
    {
      for (int job = blockIdx.x; job < 256; job += NB) {
        int b = job >> 2, hq = job & 3;
        float* awred = lds; float* alv = lds + 1024; float* cvs = lds + 1056;
        {
          int k4 = tid * 4;
          float4 s = make_float4(0.f, 0.f, 0.f, 0.f);
          for (int c = 0; c < 16; ++c) {
            float4 v = *(const float4*)&partB[(size_t)c * 69632 + b * 1088 + k4];
            s.x += v.x; s.y += v.y; s.z += v.z; s.w += v.w;
          }
          *(float4*)&awred[k4] = s;
        }
        __syncthreads();
        {
          int wv = tid >> 6, lane = tid & 63;
          for (int u = 0; u < 8; ++u) {
            int s2 = wv * 8 + u;
            const float4* orow = (const float4*)&outs[(size_t)s2 * 65536 + b * 1024];
            float pr = 0.f;
            #pragma unroll
            for (int q = 0; q < 4; ++q) {
              float4 f = orow[lane + 64 * q];
              float4 w = *(const float4*)&awred[(lane + 64 * q) * 4];
              pr += f.x * w.x + f.y * w.y + f.z * w.z + f.w * w.w;
            }
            #pragma unroll
            for (int off = 32; off > 0; off >>= 1) pr += __shfl_xor(pr, off);
            if (lane == 0) alv[s2] = pr;
          }
        }
        __syncthreads();
        if (tid < 64) {
          int len = p.qlen[b];
          float v = (tid < S && tid < len) ? alv[tid] : -1e9f;
          float mx = v;
          #pragma unroll
          for (int off = 32; off > 0; off >>= 1) mx = fmaxf(mx, __shfl_xor(mx, off));
          float e = (tid < S && tid < len) ? expf(v - mx) : 0.f;
          float sm = e;
          #pragma unroll
          for (int off = 32; off > 0; off >>= 1) sm += __shfl_xor(sm, off);
          if (tid < S) cvs[tid] = e / sm;
        }
        __syncthreads();
        {
          int h = hq * 256 + tid;
          float a = 0.f;
          #pragma unroll 8
          for (int s2 = 0; s2 < S; ++s2)
            a = fmaf(cvs[s2], outs[(size_t)s2 * 65536 + b * 1024 + h], a);
          p.c_ctrl[b * 1024 + h] = a;
        }
        __syncthreads();
      }
      gsync(bar);
    }
    // ---- C4: gemmC (c_i partials) ----
    {
      auto Al = [&](int r, int k) -> float4 { return *(const float4*)&p.c_ctrl[r * 1024 + k]; };
      auto Wl = [&](int k, int j) -> float4 { return *(const float4*)&p.W_q[(size_t)k * 512 + j]; };
      for (int job = blockIdx.x; job < 128; job += NB)
        gemm_job(lds, job & 7, job >> 3, 64, 1024, Al, Wl, partC, 512);
      gsync(bar);
    }
    // ---- C5: gemmD (uwe partials, TRANSW), A = relu(red(partC)+b_q) ----
    {
      auto Al = [&](int r, int k) -> float4 {
        float4 s = *(const float4*)&p.b_q[k];
        for (int c = 0; c < 16; ++c) {
          float4 v = *(const float4*)&partC[(size_t)c * 32768 + r * 512 + k];
          s.x += v.x; s.y += v.y; s.z += v.z; s.w += v.w;
        }
        return make_float4(fmaxf(s.x, 0.f), fmaxf(s.y, 0.f), fmaxf(s.z, 0.f), fmaxf(s.w, 0.f));
      };
      auto Wl = [&](int j, int k) -> float4 {
        if (j < 512) return *(const float4*)&p.W_find[(size_t)j * 512 + k];
        if (j < 528) return *(const float4*)&p.edge_cat[(size_t)(j - 512) * 512 + k];
        return make_float4(0.f, 0.f, 0.f, 0.f);
      };
      for (int job = blockIdx.x; job < 72; job += NB)
        gemm_job_t(lds, job % 9, job / 9, 64, 512, Al, Wl, partD, 576);
      gsync(bar);
    }
    // ---- C6a: prep (per-b) + uwe reduce ----
    {
      for (int job = blockIdx.x; job < 196; job += NB) {
        if (job < 64) {
          int b = job;
          if (tid < 16) {
            float s = 0.f;
            for (int c = 0; c < 8; ++c) s += partD[(size_t)c * 36864 + b * 576 + 512 + tid];
            lds[tid] = s;
          } else if (tid < 22) {
            int m = tid - 16; float s = 0.f;
            for (int c = 0; c < 16; ++c) s += partB[(size_t)c * 69632 + b * 1088 + 1024 + m];
            lds[tid] = s;
          }
          __syncthreads();
          if (tid == 0) {
            float mx = lds[0];
            for (int e = 1; e < NE; ++e) mx = fmaxf(mx, lds[e]);
            float sm = 0.f, ex[NE];
            for (int e = 0; e < NE; ++e) { ex[e] = expf(lds[e] - mx); sm += ex[e]; }
            for (int e = 0; e < NE; ++e) p.we[b * NE + e] = ex[e] / sm;
            float mx2 = lds[16];
            for (int m = 1; m < MM; ++m) mx2 = fmaxf(mx2, lds[16 + m]);
            float e6[MM], sm2 = 0.f;
            for (int m = 0; m < MM; ++m) { e6[m] = expf(lds[16 + m] - mx2); sm2 += e6[m]; }
            float p0 = p.sptr[b * 4 + 0], p1 = p.sptr[b * 4 + 1];
            float p2 = p.sptr[b * 4 + 2], p3 = p.sptr[b * 4 + 3];
            float sp[12];
            sp[0] = p0; sp[1] = p1; sp[2] = p2; sp[3] = p3;
            sp[4] = 0.f;      sp[5] = p0; sp[6] = p1; sp[7] = p2 + p3;
            sp[8] = p0 + p1;  sp[9] = p2; sp[10] = p3; sp[11] = 0.f;
            for (int i = 0; i < 12; ++i) { p.spv[b * 12 + i] = sp[i]; lds[22 + i] = sp[i]; }
            float val[MM];
            val[0] = rintf(p0 + p1 + p2 + p3);
            val[1] = rintf(p0 + p1 + p2);
            val[2] = rintf(p1 + p2 + p3);
            val[3] = val[2];
            val[4] = rintf(p2 + p3);
            val[5] = val[2];
            float mpv[MM], ssum = 0.f;
            #pragma unroll
            for (int m = 0; m < MM; ++m) { mpv[m] = (e6[m] / sm2) * val[m]; ssum += mpv[m]; }
            float inv = (ssum > 0.f) ? 1.f / ssum : 1.f;
            #pragma unroll
            for (int m = 0; m < MM; ++m) p.mp[b * MM + m] = mpv[m] * inv;
          }
          __syncthreads();
          if (tid < 128) {
            float4 st = *(const float4*)&p.att_stack[(b * NN + tid) * LL];
            float ainv = st.x * lds[22] + st.y * lds[23] + st.z * lds[24] + st.w * lds[25];
            float ap   = st.x * lds[30] + st.y * lds[31] + st.z * lds[32] + st.w * lds[33];
            p.ain[b * NN + tid] = ainv;
            p.aw4[b * NN + tid] = fminf(ap, ainv);
            float t2 = ainv;
            #pragma unroll
            for (int off = 32; off > 0; off >>= 1) t2 += __shfl_xor(t2, off);
            if ((tid & 63) == 0) lds[40 + (tid >> 6)] = t2;
          }
          __syncthreads();
          if (tid == 0) p.asum[b] = lds[40] + lds[41] + 1e-6f;
          __syncthreads();
        } else {
          int idx = (job - 64) * 256 + tid;   // < 33792
          int b = idx / 528, col = idx - b * 528;
          float s = 0.f;
          for (int c = 0; c < 8; ++c) s += partD[(size_t)c * 36864 + b * 576 + col];
          p.uwe[b * 528 + col] = s;
          __syncthreads();
        }
      }
      gsync(bar);
    }
    // ---- C6b: afind + atrans + pooled ----
    {
      for (int job = blockIdx.x; job < 2688; job += NB) {
        if (job < 2048) {
          int gw = job * 4 + (tid >> 6);
          int b = gw >> 7, n = gw & 127, lane = tid & 63;
          int vid = p.v_idx[b * NN + n];
          const float4* fp = (const float4*)&p.attr_emb[(size_t)vid * DV];
          const float4* up = (const float4*)&p.uwe[(size_t)b * 528];
          float pr = 0.f;
          #pragma unroll
          for (int q = 0; q < 2; ++q) {
            float4 f = fp[lane + 64 * q], u = up[lane + 64 * q];
            pr += f.x * u.x + f.y * u.y + f.z * u.z + f.w * u.w;
          }
          #pragma unroll
          for (int off = 32; off > 0; off >>= 1) pr += __shfl_xor(pr, off);
          if (lane == 0) p.afind[b * NN + n] = sigmoidf_(pr * 0.04419417382415922f);
          __syncthreads();
        } else if (job < 2560) {
          int j2 = job - 2048;
          int b = j2 >> 3, ig = j2 & 7;
          float* ainL = lds; float* wesL = lds + 128;
          if (tid < 128) ainL[tid] = p.ain[b * NN + tid];
          else if (tid < 144) wesL[tid - 128] = p.we[b * NE + tid - 128];
          __syncthreads();
          int i = ig * 16 + (tid >> 4);
          const int* crow = &p.cat_mat[((size_t)b * NN + i) * NN];
          const float* nrow = &p.conn[((size_t)b * NN + i) * NN];
          float a = 0.f;
          #pragma unroll
          for (int q = 0; q < 8; ++q) {
            int j = (tid & 15) + 16 * q;
            a = fmaf(wesL[crow[j]] * nrow[j], ainL[j], a);
          }
          a += __shfl_xor(a, 1); a += __shfl_xor(a, 2); a += __shfl_xor(a, 4); a += __shfl_xor(a, 8);
          if ((tid & 15) == 0) p.atr[b * NN + i] = fminf(a, 1.f);
          __syncthreads();
        } else {
          int j3 = job - 2560;
          int b = j3 >> 1, d = (j3 & 1) * 256 + tid;
          float* ainL = lds; int* vidL = (int*)(lds + 128);
          if (tid < 128) { ainL[tid] = p.ain[b * NN + tid]; vidL[tid] = p.v_idx[b * NN + tid]; }
          __syncthreads();
          float a = 0.f;
          #pragma unroll 4
          for (int n = 0; n < NN; ++n)
            a = fmaf(ainL[n], p.attr_emb[(size_t)vidL[n] * DV + d], a);
          p.pooled[b * DV + d] = a / p.asum[b];
          __syncthreads();
        }
      }
      gsync(bar);
    }
    // ---- C7: gemmE (pooled @ W_desc partials) + stack/ptr update ----
    {
      auto Al = [&](int r, int k) -> float4 { return *(const float4*)&p.pooled[r * 512 + k]; };
      auto Wl = [&](int k, int j) -> float4 { return *(const float4*)&p.W_desc[(size_t)k * 512 + j]; };
      for (int job = blockIdx.x; job < 192; job += NB) {
        if (job < 64) {
          gemm_job(lds, job & 7, job >> 3, 64, 512, Al, Wl, p.partE, 512);
        } else {
          int idx = (job - 64) * 256 + tid;   // < 32768
          int b = idx >> 9, e = idx & 511;
          int n = e >> 2, l = e & 3;
          const float* sp = &p.spv[b * 12]; const float* m = &p.mp[b * 6];
          float st = p.att_stack[(b * NN + n) * LL + l];
          float keep = m[0] + m[5] + m[1] * (1.f - sp[4 + l]) + (m[2] + m[3]) * (1.f - sp[l])
                     + m[4] * (1.f - sp[8 + l]);
          float af = p.afind[b * NN + n], ai2 = p.ain[b * NN + n];
          float add = sp[4 + l] * m[1] * af
                    + sp[l] * (m[2] * p.atr[b * NN + n] + m[3] * ai2 * af)
                    + sp[8 + l] * m[4] * p.aw4[b * NN + n];
          p.att_stack[(b * NN + n) * LL + l] = keep * st + add;
          if (idx < 256) {
            int b2 = idx >> 2, l2 = idx & 3;
            const float* sp2 = &p.spv[b2 * 12]; const float* m2 = &p.mp[b2 * 6];
            p.sptr[b2 * 4 + l2] = (m2[0] + m2[2] + m2[3]) * sp2[l2] + m2[1] * sp2[4 + l2]
                                + (m2[4] + m2[5]) * sp2[8 + l2];
          }
          __syncthreads();
        }
      }
      gsync(bar);
    }
  }

  // =================== classifier ===================
  // CL1: h1 partials; A = [EPI(mem) | q_hidden]
  {
    auto Al = [&](int r, int k) -> float4 {
      if (k < 512) {
        float4 s = make_float4(0.f, 0.f, 0.f, 0.f);
        for (int c = 0; c < 8; ++c) {
          float4 v = *(const float4*)&p.partE[(size_t)c * 32768 + r * 512 + k];
          s.x += v.x; s.y += v.y; s.z += v.z; s.w += v.w;
        }
        const float* m = &p.mp[r * 6];
        float s04 = m[0] + m[1] + m[2] + m[3] + m[4];
        float4 o = *(const float4*)&p.mem[r * 512 + k];
        return make_float4(s04 * o.x + m[5] * s.x, s04 * o.y + m[5] * s.y,
                           s04 * o.z + m[5] * s.z, s04 * o.w + m[5] * s.w);
      }
      int tq = p.qlen[r] - 1;
      return *(const float4*)&outs[(size_t)tq * 65536 + r * 1024 + (k - 512)];
    };
    auto Wl = [&](int k, int j) -> float4 { return *(const float4*)&p.W_cls1[(size_t)k * 1024 + j]; };
    for (int job = blockIdx.x; job < 128; job += NB)
      gemm_job(lds, job & 15, job >> 4, 192, 1536, Al, Wl, p.partH, 1024);
    gsync(bar);
  }
  // CL2: logits partials; A = relu(red(partH)+b_cls1)
  {
    auto Al = [&](int r, int k) -> float4 {
      float4 s = *(const float4*)&p.b_cls1[k];
      for (int c = 0; c < 8; ++c) {
        float4 v = *(const float4*)&p.partH[(size_t)c * 65536 + r * 1024 + k];
        s.x += v.x; s.y += v.y; s.z += v.z; s.w += v.w;
      }
      return make_float4(fmaxf(s.x, 0.f), fmaxf(s.y, 0.f), fmaxf(s.z, 0.f), fmaxf(s.w, 0.f));
    };
    auto Wl = [&](int k, int j) -> float4 {
      float v[4];
      #pragma unroll
      for (int i = 0; i < 4; ++i) { int jj = j + i; v[i] = (jj < NA) ? p.W_cls2[(size_t)k * NA + jj] : 0.f; }
      return make_float4(v[0], v[1], v[2], v[3]);
    };
    for (int job = blockIdx.x; job < 32; job += NB)
      gemm_job(lds, 0, job, 32, 1024, Al, Wl, p.partL, 64);
    gsync(bar);
  }
  // CL3: final reduce -> logits
  {
    int idx = blockIdx.x * NT + tid;
    if (idx < B * NA) {
      int r = idx / NA, j = idx - r * NA;
      float s = p.b_cls2[j];
      for (int c = 0; c < 32; ++c) s += p.partL[(size_t)c * 4096 + r * 64 + j];
      p.logits[idx] = s;
    }
  }
}

// ---- init: state + barrier + sentinel in logits (diagnoses launch failure) ----
__global__ void pre_kernel(float* c_lstm, float* c_ctrl, float* att_stack, float* mem,
                           float* sptr, int* bar, float* logits) {
  int idx = blockIdx.x * 256 + threadIdx.x;
  if (idx < B * DH) { c_lstm[idx] = 0.f; c_ctrl[idx] = 0.f; }
  if (idx < B * NN * LL) att_stack[idx] = 0.f;
  if (idx < B * DV) mem[idx] = 0.f;
  if (idx < B * LL) sptr[idx] = ((idx & (LL - 1)) == 0) ? 1.f : 0.f;
  if (idx < 64) bar[idx] = 0;
  if (idx < B * NA) logits[idx] = 12345.0f;   // overwritten by mega_kernel CL3 if it runs
}

extern "C" void kernel_launch(void* const* d_in, const int* in_sizes, int n_in,
                              void* d_out, int out_size, void* d_ws, size_t ws_size,
                              hipStream_t stream) {
  KP p;
  p.questions = (const int*)d_in[0];
  p.qlen      = (const int*)d_in[1];
  p.conn      = (const float*)d_in[2];
  p.cat_mat   = (const int*)d_in[3];
  p.v_idx     = (const int*)d_in[4];
  p.attr_emb  = (const float*)d_in[5];
  p.edge_cat  = (const float*)d_in[6];
  p.enc_emb   = (const float*)d_in[7];
  p.Wx        = (const float*)d_in[8];
  p.Wh        = (const float*)d_in[9];
  p.b_lstm    = (const float*)d_in[10];
  p.W_cq      = (const float*)d_in[11];
  p.b_cq      = (const float*)d_in[12];
  p.W_mod     = (const float*)d_in[13];
  p.W_att     = (const float*)d_in[14];
  p.W_q       = (const float*)d_in[15];
  p.b_q       = (const float*)d_in[16];
  p.W_find    = (const float*)d_in[17];
  p.W_desc    = (const float*)d_in[18];
  p.W_cls1    = (const float*)d_in[19];
  p.b_cls1    = (const float*)d_in[20];
  p.W_cls2    = (const float*)d_in[21];
  p.b_cls2    = (const float*)d_in[22];
  p.logits    = (float*)d_out;

  float* w = (float*)d_ws;
  size_t off = 0;
  p.outs      = w + off; off += (size_t)S * B * DH;    // 2,097,152
  p.share     = w + off; off += 2457600;               // partLSTM/A/B/C/D union
  p.partE     = w + off; off += 262144;
  p.partH     = w + off; off += 524288;
  p.partL     = w + off; off += 131072;
  p.c_ctrl    = w + off; off += B * DH;
  p.c_lstm    = w + off; off += B * DH;
  p.uwe       = w + off; off += B * 528;
  p.we        = w + off; off += B * NE;
  p.mp        = w + off; off += B * MM;
  p.spv       = w + off; off += B * 12;
  p.ain       = w + off; off += B * NN;
  p.aw4       = w + off; off += B * NN;
  p.afind     = w + off; off += B * NN;
  p.atr       = w + off; off += B * NN;
  p.asum      = w + off; off += B;
  p.att_stack = w + off; off += B * NN * LL;
  p.sptr      = w + off; off += B * LL;
  p.mem       = w + off; off += B * DV;
  p.pooled    = w + off; off += B * DV;
  p.bar       = (int*)(w + off); off += 64;

  pre_kernel<<<256, 256, 0, stream>>>(p.c_lstm, p.c_ctrl, p.att_stack, p.mem, p.sptr, p.bar,
                                      p.logits);

  void* args[] = { &p };
  hipError_t cerr = hipLaunchCooperativeKernel(reinterpret_cast<void*>(mega_kernel),
                                               dim3(NB), dim3(NT), args, 0, stream);
  if (cerr != hipSuccess) {
    (void)hipGetLastError();   // clear sticky error state
    // Fallback: plain launch. Co-residency of all 512 blocks is guaranteed by
    // __launch_bounds__(256,2) (<=256 VGPR, 16.6KB LDS -> 2 blocks/CU x 256 CU),
    // so the spin barrier remains safe.
    hipLaunchKernelGGL(mega_kernel, dim3(NB), dim3(NT), 0, stream, p);
  }
}

// Round 7
// 4940.677 us; speedup vs baseline: 4.3218x; 4.3218x over previous
//
#include <hip/hip_runtime.h>
#include <math.h>

#define B 64
#define S 32
#define NN 128
#define DV 512
#define DW 300
#define DH 1024
#define CLS 1024
#define T_CTRL 12
#define LL 4
#define NA 28
#define NE 16
#define MM 6
#define NB 512
#define NT 256

__device__ __forceinline__ float sigmoidf_(float x) { return 1.0f / (1.0f + expf(-x)); }

struct KP {
  const int* questions; const int* qlen;
  const float* conn; const int* cat_mat; const int* v_idx;
  const float* attr_emb; const float* edge_cat; const float* enc_emb;
  const float* Wx; const float* Wh; const float* b_lstm;
  const float* W_cq; const float* b_cq; const float* W_mod; const float* W_att;
  const float* W_q; const float* b_q; const float* W_find; const float* W_desc;
  const float* W_cls1; const float* b_cls1; const float* W_cls2; const float* b_cls2;
  float* outs; float* share; float* partE; float* partH; float* partL;
  float* c_ctrl; float* c_lstm; float* uwe; float* we; float* mp; float* spv;
  float* ain; float* aw4; float* afind; float* atr; float* asum;
  float* att_stack; float* sptr; float* mem; float* pooled;
  int* bar; float* logits;
};

// ---- grid barrier (agent scope), minimal-coherence version ----
// Poll with RELAXED loads (no per-poll cache invalidate); exactly one
// release-writeback (folded into fetch_add) and one acquire-invalidate
// (explicit amdgcn fence) per block per barrier. tid 0 only.
__device__ __forceinline__ void gsync(int* bar) {
  __syncthreads();
  if (threadIdx.x == 0) {
    int* cnt = bar; int* gen = bar + 32;
    int g = __hip_atomic_load(gen, __ATOMIC_RELAXED, __HIP_MEMORY_SCOPE_AGENT);
    int prev = __hip_atomic_fetch_add(cnt, 1, __ATOMIC_RELEASE, __HIP_MEMORY_SCOPE_AGENT);
    if (prev == NB - 1) {
      __hip_atomic_store(cnt, 0, __ATOMIC_RELAXED, __HIP_MEMORY_SCOPE_AGENT);
      __hip_atomic_fetch_add(gen, 1, __ATOMIC_RELEASE, __HIP_MEMORY_SCOPE_AGENT);
    } else {
      while (__hip_atomic_load(gen, __ATOMIC_RELAXED, __HIP_MEMORY_SCOPE_AGENT) == g)
        __builtin_amdgcn_s_sleep(16);
    }
    __builtin_amdgcn_fence(__ATOMIC_ACQUIRE, "agent");   // one buffer_inv
  }
  __syncthreads();
}

// ---- one 64x64-tile K-chunk GEMM job. Ast [32][65], Ws [32][64] in lds ----
template<class AF, class WF>
__device__ __forceinline__ void gemm_job(float* lds, int tile, int chunk, int Kc, int K,
                                         AF&& loadA, WF&& loadW, float* part, int Cld) {
  float* Ast = lds;
  float* Ws  = lds + 2080;
  const int tid = threadIdx.x;
  const int j0 = tile * 64;
  const int kbeg = chunk * Kc;
  const int kend = (kbeg + Kc < K) ? (kbeg + Kc) : K;
  const int rg = tid & 15, cg = tid >> 4;
  float acc[4][4] = {};
  for (int kt = kbeg; kt < kend; kt += 32) {
    #pragma unroll
    for (int i2 = 0; i2 < 2; ++i2) {
      int idx = tid + i2 * 256;
      int r = idx >> 3, k4 = (idx & 7) * 4;
      float4 av = loadA(r, kt + k4);
      Ast[(k4 + 0) * 65 + r] = av.x; Ast[(k4 + 1) * 65 + r] = av.y;
      Ast[(k4 + 2) * 65 + r] = av.z; Ast[(k4 + 3) * 65 + r] = av.w;
    }
    #pragma unroll
    for (int i2 = 0; i2 < 2; ++i2) {
      int idx = tid + i2 * 256;
      int kk = idx >> 4, j4 = (idx & 15) * 4;
      float4 wv = loadW(kt + kk, j0 + j4);
      *(float4*)&Ws[kk * 64 + j4] = wv;
    }
    __syncthreads();
    #pragma unroll
    for (int k = 0; k < 32; ++k) {
      float a0 = Ast[k*65+rg], a1 = Ast[k*65+rg+16], a2 = Ast[k*65+rg+32], a3 = Ast[k*65+rg+48];
      float4 w = *(const float4*)&Ws[k*64 + cg*4];
      acc[0][0]=fmaf(a0,w.x,acc[0][0]); acc[0][1]=fmaf(a0,w.y,acc[0][1]); acc[0][2]=fmaf(a0,w.z,acc[0][2]); acc[0][3]=fmaf(a0,w.w,acc[0][3]);
      acc[1][0]=fmaf(a1,w.x,acc[1][0]); acc[1][1]=fmaf(a1,w.y,acc[1][1]); acc[1][2]=fmaf(a1,w.z,acc[1][2]); acc[1][3]=fmaf(a1,w.w,acc[1][3]);
      acc[2][0]=fmaf(a2,w.x,acc[2][0]); acc[2][1]=fmaf(a2,w.y,acc[2][1]); acc[2][2]=fmaf(a2,w.z,acc[2][2]); acc[2][3]=fmaf(a2,w.w,acc[2][3]);
      acc[3][0]=fmaf(a3,w.x,acc[3][0]); acc[3][1]=fmaf(a3,w.y,acc[3][1]); acc[3][2]=fmaf(a3,w.z,acc[3][2]); acc[3][3]=fmaf(a3,w.w,acc[3][3]);
    }
    __syncthreads();
  }
  float* op = part + (size_t)chunk * 64 * Cld + j0 + cg * 4;
  #pragma unroll
  for (int m = 0; m < 4; ++m)
    *(float4*)&op[(size_t)(rg + 16 * m) * Cld] = make_float4(acc[m][0], acc[m][1], acc[m][2], acc[m][3]);
}

// ---- TRANSW variant: loadWT(j,k) returns float4 along k ----
template<class AF, class WF>
__device__ __forceinline__ void gemm_job_t(float* lds, int tile, int chunk, int Kc, int K,
                                           AF&& loadA, WF&& loadWT, float* part, int Cld) {
  float* Ast = lds;
  float* Ws  = lds + 2080;
  const int tid = threadIdx.x;
  const int j0 = tile * 64;
  const int kbeg = chunk * Kc;
  const int kend = (kbeg + Kc < K) ? (kbeg + Kc) : K;
  const int rg = tid & 15, cg = tid >> 4;
  float acc[4][4] = {};
  for (int kt = kbeg; kt < kend; kt += 32) {
    #pragma unroll
    for (int i2 = 0; i2 < 2; ++i2) {
      int idx = tid + i2 * 256;
      int r = idx >> 3, k4 = (idx & 7) * 4;
      float4 av = loadA(r, kt + k4);
      Ast[(k4 + 0) * 65 + r] = av.x; Ast[(k4 + 1) * 65 + r] = av.y;
      Ast[(k4 + 2) * 65 + r] = av.z; Ast[(k4 + 3) * 65 + r] = av.w;
    }
    #pragma unroll
    for (int i2 = 0; i2 < 2; ++i2) {
      int idx = tid + i2 * 256;
      int jloc = idx >> 3, k4 = (idx & 7) * 4;
      float4 wv = loadWT(j0 + jloc, kt + k4);
      Ws[(k4+0)*64 + jloc] = wv.x; Ws[(k4+1)*64 + jloc] = wv.y;
      Ws[(k4+2)*64 + jloc] = wv.z; Ws[(k4+3)*64 + jloc] = wv.w;
    }
    __syncthreads();
    #pragma unroll
    for (int k = 0; k < 32; ++k) {
      float a0 = Ast[k*65+rg], a1 = Ast[k*65+rg+16], a2 = Ast[k*65+rg+32], a3 = Ast[k*65+rg+48];
      float4 w = *(const float4*)&Ws[k*64 + cg*4];
      acc[0][0]=fmaf(a0,w.x,acc[0][0]); acc[0][1]=fmaf(a0,w.y,acc[0][1]); acc[0][2]=fmaf(a0,w.z,acc[0][2]); acc[0][3]=fmaf(a0,w.w,acc[0][3]);
      acc[1][0]=fmaf(a1,w.x,acc[1][0]); acc[1][1]=fmaf(a1,w.y,acc[1][1]); acc[1][2]=fmaf(a1,w.z,acc[1][2]); acc[1][3]=fmaf(a1,w.w,acc[1][3]);
      acc[2][0]=fmaf(a2,w.x,acc[2][0]); acc[2][1]=fmaf(a2,w.y,acc[2][1]); acc[2][2]=fmaf(a2,w.z,acc[2][2]); acc[2][3]=fmaf(a2,w.w,acc[2][3]);
      acc[3][0]=fmaf(a3,w.x,acc[3][0]); acc[3][1]=fmaf(a3,w.y,acc[3][1]); acc[3][2]=fmaf(a3,w.z,acc[3][2]); acc[3][3]=fmaf(a3,w.w,acc[3][3]);
    }
    __syncthreads();
  }
  float* op = part + (size_t)chunk * 64 * Cld + j0 + cg * 4;
  #pragma unroll
  for (int m = 0; m < 4; ++m)
    *(float4*)&op[(size_t)(rg + 16 * m) * Cld] = make_float4(acc[m][0], acc[m][1], acc[m][2], acc[m][3]);
}

__global__ __launch_bounds__(NT, 2) void mega_kernel(KP p) {
  __shared__ float lds[4160];
  const int tid = threadIdx.x;
  int* bar = p.bar;
  float* partLSTM = p.share;                 // [7][64][4096]
  float* partA = p.share;                    // [8][64][1024]
  float* partB = p.share + 524288;           // [16][64][1088]
  float* partC = p.share + 1638400;          // [16][64][512]
  float* partD = p.share + 2162688;          // [8][64][576]
  float* outs = p.outs;

  // =================== LSTM ===================
  for (int t = 0; t < S; ++t) {
    const int K = (t == 0) ? 320 : 1344;
    const int SKt = (t == 0) ? 2 : 7;
    const int njobs = 64 * SKt;
    auto Al = [&](int r, int k) -> float4 {
      if (k < 320) {
        if (k < 300) { int qid = p.questions[r * 32 + t];
                       return *(const float4*)&p.enc_emb[(size_t)qid * 300 + k]; }
        return make_float4(0.f, 0.f, 0.f, 0.f);
      }
      return *(const float4*)&outs[(size_t)(t - 1) * 65536 + r * 1024 + (k - 320)];
    };
    auto Wl = [&](int k, int j) -> float4 {
      if (k < 300) return *(const float4*)&p.Wx[(size_t)k * 4096 + j];
      if (k < 320) return make_float4(0.f, 0.f, 0.f, 0.f);
      return *(const float4*)&p.Wh[(size_t)(k - 320) * 4096 + j];
    };
    for (int job = blockIdx.x; job < njobs; job += NB)
      gemm_job(lds, job & 63, job >> 6, 192, K, Al, Wl, partLSTM, 4096);
    gsync(bar);
    // gates
    {
      int idx = blockIdx.x * NT + tid;
      if (idx < 65536) {
        int b = idx >> 10, j = idx & 1023;
        float gi = 0.f, gf = 0.f, gg = 0.f, go = 0.f;
        for (int c = 0; c < SKt; ++c) {
          const float* pp = partLSTM + (size_t)c * 262144 + b * 4096;
          gi += pp[j]; gf += pp[1024 + j]; gg += pp[2048 + j]; go += pp[3072 + j];
        }
        gi += p.b_lstm[j]; gf += p.b_lstm[1024 + j]; gg += p.b_lstm[2048 + j]; go += p.b_lstm[3072 + j];
        float cc = sigmoidf_(gf) * p.c_lstm[idx] + sigmoidf_(gi) * tanhf(gg);
        outs[(size_t)t * 65536 + idx] = sigmoidf_(go) * tanhf(cc);
        p.c_lstm[idx] = cc;
      }
    }
    gsync(bar);
  }

  // =================== control loop ===================
  for (int it = 0; it < T_CTRL; ++it) {
    // ---- C1: gemmA (cq partials) + redE of previous iter ----
    {
      auto Al = [&](int r, int k) -> float4 {
        if (k < 1024) return *(const float4*)&p.c_ctrl[r * 1024 + k];
        int tq = p.qlen[r] - 1;
        return *(const float4*)&outs[(size_t)tq * 65536 + r * 1024 + (k - 1024)];
      };
      auto Wl = [&](int k, int j) -> float4 {
        return *(const float4*)&p.W_cq[(size_t)k * 1024 + j];
      };
      int njobs = (it > 0) ? 256 : 128;
      for (int job = blockIdx.x; job < njobs; job += NB) {
        if (job < 128) {
          gemm_job(lds, job & 15, job >> 4, 256, 2048, Al, Wl, partA, 1024);
        } else {
          int idx = (job - 128) * 256 + tid;   // < 32768
          int b = idx >> 9, jj = idx & 511;
          const float* m = &p.mp[b * 6];
          float s04 = m[0] + m[1] + m[2] + m[3] + m[4];
          float s = 0.f;
          for (int c = 0; c < 8; ++c) s += p.partE[(size_t)c * 32768 + b * 512 + jj];
          p.mem[b * 512 + jj] = s04 * p.mem[b * 512 + jj] + m[5] * s;
          __syncthreads();
        }
      }
      gsync(bar);
    }
    // ---- C2: gemmB (am partials), A = tanh(red(partA)+b_cq) ----
    {
      auto Al = [&](int r, int k) -> float4 {
        float4 s = *(const float4*)&p.b_cq[k];
        for (int c = 0; c < 8; ++c) {
          float4 v = *(const float4*)&partA[(size_t)c * 65536 + r * 1024 + k];
          s.x += v.x; s.y += v.y; s.z += v.z; s.w += v.w;
        }
        return make_float4(tanhf(s.x), tanhf(s.y), tanhf(s.z), tanhf(s.w));
      };
      auto Wl = [&](int k, int j) -> float4 {
        if (j < 1024) return *(const float4*)&p.W_att[(size_t)k * 1024 + j];
        float v[4];
        #pragma unroll
        for (int i = 0; i < 4; ++i) {
          int jj = j + i;
          v[i] = (jj < 1030) ? p.W_mod[(size_t)k * 6 + (jj - 1024)] : 0.f;
        }
        return make_float4(v[0], v[1], v[2], v[3]);
      };
      for (int job = blockIdx.x; job < 272; job += NB)
        gemm_job(lds, job % 17, job / 17, 64, 1024, Al, Wl, partB, 1088);
      gsync(bar);
    }
    // ---- C3: attention (reduce attW, al, softmax, c_ctrl) ----
    {
      for (int job = blockIdx.x; job < 256; job += NB) {
        int b = job >> 2, hq = job & 3;
        float* awred = lds; float* alv = lds + 1024; float* cvs = lds + 1056;
        {
          int k4 = tid * 4;
          float4 s = make_float4(0.f, 0.f, 0.f, 0.f);
          for (int c = 0; c < 16; ++c) {
            float4 v = *(const float4*)&partB[(size_t)c * 69632 + b * 1088 + k4];
            s.x += v.x; s.y += v.y; s.z += v.z; s.w += v.w;
          }
          *(float4*)&awred[k4] = s;
        }
        __syncthreads();
        {
          int wv = tid >> 6, lane = tid & 63;
          for (int u = 0; u < 8; ++u) {
            int s2 = wv * 8 + u;
            const float4* orow = (const float4*)&outs[(size_t)s2 * 65536 + b * 1024];
            float pr = 0.f;
            #pragma unroll
            for (int q = 0; q < 4; ++q) {
              float4 f = orow[lane + 64 * q];
              float4 w = *(const float4*)&awred[(lane + 64 * q) * 4];
              pr += f.x * w.x + f.y * w.y + f.z * w.z + f.w * w.w;
            }
            #pragma unroll
            for (int off = 32; off > 0; off >>= 1) pr += __shfl_xor(pr, off);
            if (lane == 0) alv[s2] = pr;
          }
        }
        __syncthreads();
        if (tid < 64) {
          int len = p.qlen[b];
          float v = (tid < S && tid < len) ? alv[tid] : -1e9f;
          float mx = v;
          #pragma unroll
          for (int off = 32; off > 0; off >>= 1) mx = fmaxf(mx, __shfl_xor(mx, off));
          float e = (tid < S && tid < len) ? expf(v - mx) : 0.f;
          float sm = e;
          #pragma unroll
          for (int off = 32; off > 0; off >>= 1) sm += __shfl_xor(sm, off);
          if (tid < S) cvs[tid] = e / sm;
        }
        __syncthreads();
        {
          int h = hq * 256 + tid;
          float a = 0.f;
          #pragma unroll 8
          for (int s2 = 0; s2 < S; ++s2)
            a = fmaf(cvs[s2], outs[(size_t)s2 * 65536 + b * 1024 + h], a);
          p.c_ctrl[b * 1024 + h] = a;
        }
        __syncthreads();
      }
      gsync(bar);
    }
    // ---- C4: gemmC (c_i partials) ----
    {
      auto Al = [&](int r, int k) -> float4 { return *(const float4*)&p.c_ctrl[r * 1024 + k]; };
      auto Wl = [&](int k, int j) -> float4 { return *(const float4*)&p.W_q[(size_t)k * 512 + j]; };
      for (int job = blockIdx.x; job < 128; job += NB)
        gemm_job(lds, job & 7, job >> 3, 64, 1024, Al, Wl, partC, 512);
      gsync(bar);
    }
    // ---- C5: gemmD (uwe partials, TRANSW), A = relu(red(partC)+b_q) ----
    {
      auto Al = [&](int r, int k) -> float4 {
        float4 s = *(const float4*)&p.b_q[k];
        for (int c = 0; c < 16; ++c) {
          float4 v = *(const float4*)&partC[(size_t)c * 32768 + r * 512 + k];
          s.x += v.x; s.y += v.y; s.z += v.z; s.w += v.w;
        }
        return make_float4(fmaxf(s.x, 0.f), fmaxf(s.y, 0.f), fmaxf(s.z, 0.f), fmaxf(s.w, 0.f));
      };
      auto Wl = [&](int j, int k) -> float4 {
        if (j < 512) return *(const float4*)&p.W_find[(size_t)j * 512 + k];
        if (j < 528) return *(const float4*)&p.edge_cat[(size_t)(j - 512) * 512 + k];
        return make_float4(0.f, 0.f, 0.f, 0.f);
      };
      for (int job = blockIdx.x; job < 72; job += NB)
        gemm_job_t(lds, job % 9, job / 9, 64, 512, Al, Wl, partD, 576);
      gsync(bar);
    }
    // ---- C6a: prep (per-b) + uwe reduce ----
    {
      for (int job = blockIdx.x; job < 196; job += NB) {
        if (job < 64) {
          int b = job;
          if (tid < 16) {
            float s = 0.f;
            for (int c = 0; c < 8; ++c) s += partD[(size_t)c * 36864 + b * 576 + 512 + tid];
            lds[tid] = s;
          } else if (tid < 22) {
            int m = tid - 16; float s = 0.f;
            for (int c = 0; c < 16; ++c) s += partB[(size_t)c * 69632 + b * 1088 + 1024 + m];
            lds[tid] = s;
          }
          __syncthreads();
          if (tid == 0) {
            float mx = lds[0];
            for (int e = 1; e < NE; ++e) mx = fmaxf(mx, lds[e]);
            float sm = 0.f, ex[NE];
            for (int e = 0; e < NE; ++e) { ex[e] = expf(lds[e] - mx); sm += ex[e]; }
            for (int e = 0; e < NE; ++e) p.we[b * NE + e] = ex[e] / sm;
            float mx2 = lds[16];
            for (int m = 1; m < MM; ++m) mx2 = fmaxf(mx2, lds[16 + m]);
            float e6[MM], sm2 = 0.f;
            for (int m = 0; m < MM; ++m) { e6[m] = expf(lds[16 + m] - mx2); sm2 += e6[m]; }
            float p0 = p.sptr[b * 4 + 0], p1 = p.sptr[b * 4 + 1];
            float p2 = p.sptr[b * 4 + 2], p3 = p.sptr[b * 4 + 3];
            float sp[12];
            sp[0] = p0; sp[1] = p1; sp[2] = p2; sp[3] = p3;
            sp[4] = 0.f;      sp[5] = p0; sp[6] = p1; sp[7] = p2 + p3;
            sp[8] = p0 + p1;  sp[9] = p2; sp[10] = p3; sp[11] = 0.f;
            for (int i = 0; i < 12; ++i) { p.spv[b * 12 + i] = sp[i]; lds[22 + i] = sp[i]; }
            float val[MM];
            val[0] = rintf(p0 + p1 + p2 + p3);
            val[1] = rintf(p0 + p1 + p2);
            val[2] = rintf(p1 + p2 + p3);
            val[3] = val[2];
            val[4] = rintf(p2 + p3);
            val[5] = val[2];
            float mpv[MM], ssum = 0.f;
            #pragma unroll
            for (int m = 0; m < MM; ++m) { mpv[m] = (e6[m] / sm2) * val[m]; ssum += mpv[m]; }
            float inv = (ssum > 0.f) ? 1.f / ssum : 1.f;
            #pragma unroll
            for (int m = 0; m < MM; ++m) p.mp[b * MM + m] = mpv[m] * inv;
          }
          __syncthreads();
          if (tid < 128) {
            float4 st = *(const float4*)&p.att_stack[(b * NN + tid) * LL];
            float ainv = st.x * lds[22] + st.y * lds[23] + st.z * lds[24] + st.w * lds[25];
            float ap   = st.x * lds[30] + st.y * lds[31] + st.z * lds[32] + st.w * lds[33];
            p.ain[b * NN + tid] = ainv;
            p.aw4[b * NN + tid] = fminf(ap, ainv);
            float t2 = ainv;
            #pragma unroll
            for (int off = 32; off > 0; off >>= 1) t2 += __shfl_xor(t2, off);
            if ((tid & 63) == 0) lds[40 + (tid >> 6)] = t2;
          }
          __syncthreads();
          if (tid == 0) p.asum[b] = lds[40] + lds[41] + 1e-6f;
          __syncthreads();
        } else {
          int idx = (job - 64) * 256 + tid;   // < 33792
          int b = idx / 528, col = idx - b * 528;
          float s = 0.f;
          for (int c = 0; c < 8; ++c) s += partD[(size_t)c * 36864 + b * 576 + col];
          p.uwe[b * 528 + col] = s;
          __syncthreads();
        }
      }
      gsync(bar);
    }
    // ---- C6b: afind + atrans + pooled ----
    {
      for (int job = blockIdx.x; job < 2688; job += NB) {
        if (job < 2048) {
          int gw = job * 4 + (tid >> 6);
          int b = gw >> 7, n = gw & 127, lane = tid & 63;
          int vid = p.v_idx[b * NN + n];
          const float4* fp = (const float4*)&p.attr_emb[(size_t)vid * DV];
          const float4* up = (const float4*)&p.uwe[(size_t)b * 528];
          float pr = 0.f;
          #pragma unroll
          for (int q = 0; q < 2; ++q) {
            float4 f = fp[lane + 64 * q], u = up[lane + 64 * q];
            pr += f.x * u.x + f.y * u.y + f.z * u.z + f.w * u.w;
          }
          #pragma unroll
          for (int off = 32; off > 0; off >>= 1) pr += __shfl_xor(pr, off);
          if (lane == 0) p.afind[b * NN + n] = sigmoidf_(pr * 0.04419417382415922f);
          __syncthreads();
        } else if (job < 2560) {
          int j2 = job - 2048;
          int b = j2 >> 3, ig = j2 & 7;
          float* ainL = lds; float* wesL = lds + 128;
          if (tid < 128) ainL[tid] = p.ain[b * NN + tid];
          else if (tid < 144) wesL[tid - 128] = p.we[b * NE + tid - 128];
          __syncthreads();
          int i = ig * 16 + (tid >> 4);
          const int* crow = &p.cat_mat[((size_t)b * NN + i) * NN];
          const float* nrow = &p.conn[((size_t)b * NN + i) * NN];
          float a = 0.f;
          #pragma unroll
          for (int q = 0; q < 8; ++q) {
            int j = (tid & 15) + 16 * q;
            a = fmaf(wesL[crow[j]] * nrow[j], ainL[j], a);
          }
          a += __shfl_xor(a, 1); a += __shfl_xor(a, 2); a += __shfl_xor(a, 4); a += __shfl_xor(a, 8);
          if ((tid & 15) == 0) p.atr[b * NN + i] = fminf(a, 1.f);
          __syncthreads();
        } else {
          int j3 = job - 2560;
          int b = j3 >> 1, d = (j3 & 1) * 256 + tid;
          float* ainL = lds; int* vidL = (int*)(lds + 128);
          if (tid < 128) { ainL[tid] = p.ain[b * NN + tid]; vidL[tid] = p.v_idx[b * NN + tid]; }
          __syncthreads();
          float a = 0.f;
          #pragma unroll 4
          for (int n = 0; n < NN; ++n)
            a = fmaf(ainL[n], p.attr_emb[(size_t)vidL[n] * DV + d], a);
          p.pooled[b * DV + d] = a / p.asum[b];
          __syncthreads();
        }
      }
      gsync(bar);
    }
    // ---- C7: gemmE (pooled @ W_desc partials) + stack/ptr update ----
    {
      auto Al = [&](int r, int k) -> float4 { return *(const float4*)&p.pooled[r * 512 + k]; };
      auto Wl = [&](int k, int j) -> float4 { return *(const float4*)&p.W_desc[(size_t)k * 512 + j]; };
      for (int job = blockIdx.x; job < 192; job += NB) {
        if (job < 64) {
          gemm_job(lds, job & 7, job >> 3, 64, 512, Al, Wl, p.partE, 512);
        } else {
          int idx = (job - 64) * 256 + tid;   // < 32768
          int b = idx >> 9, e = idx & 511;
          int n = e >> 2, l = e & 3;
          const float* sp = &p.spv[b * 12]; const float* m = &p.mp[b * 6];
          float st = p.att_stack[(b * NN + n) * LL + l];
          float keep = m[0] + m[5] + m[1] * (1.f - sp[4 + l]) + (m[2] + m[3]) * (1.f - sp[l])
                     + m[4] * (1.f - sp[8 + l]);
          float af = p.afind[b * NN + n], ai2 = p.ain[b * NN + n];
          float add = sp[4 + l] * m[1] * af
                    + sp[l] * (m[2] * p.atr[b * NN + n] + m[3] * ai2 * af)
                    + sp[8 + l] * m[4] * p.aw4[b * NN + n];
          p.att_stack[(b * NN + n) * LL + l] = keep * st + add;
          if (idx < 256) {
            int b2 = idx >> 2, l2 = idx & 3;
            const float* sp2 = &p.spv[b2 * 12]; const float* m2 = &p.mp[b2 * 6];
            p.sptr[b2 * 4 + l2] = (m2[0] + m2[2] + m2[3]) * sp2[l2] + m2[1] * sp2[4 + l2]
                                + (m2[4] + m2[5]) * sp2[8 + l2];
          }
          __syncthreads();
        }
      }
      gsync(bar);
    }
  }

  // =================== classifier ===================
  // CL1: h1 partials; A = [EPI(mem) | q_hidden]
  {
    auto Al = [&](int r, int k) -> float4 {
      if (k < 512) {
        float4 s = make_float4(0.f, 0.f, 0.f, 0.f);
        for (int c = 0; c < 8; ++c) {
          float4 v = *(const float4*)&p.partE[(size_t)c * 32768 + r * 512 + k];
          s.x += v.x; s.y += v.y; s.z += v.z; s.w += v.w;
        }
        const float* m = &p.mp[r * 6];
        float s04 = m[0] + m[1] + m[2] + m[3] + m[4];
        float4 o = *(const float4*)&p.mem[r * 512 + k];
        return make_float4(s04 * o.x + m[5] * s.x, s04 * o.y + m[5] * s.y,
                           s04 * o.z + m[5] * s.z, s04 * o.w + m[5] * s.w);
      }
      int tq = p.qlen[r] - 1;
      return *(const float4*)&outs[(size_t)tq * 65536 + r * 1024 + (k - 512)];
    };
    auto Wl = [&](int k, int j) -> float4 { return *(const float4*)&p.W_cls1[(size_t)k * 1024 + j]; };
    for (int job = blockIdx.x; job < 128; job += NB)
      gemm_job(lds, job & 15, job >> 4, 192, 1536, Al, Wl, p.partH, 1024);
    gsync(bar);
  }
  // CL2: logits partials; A = relu(red(partH)+b_cls1)
  {
    auto Al = [&](int r, int k) -> float4 {
      float4 s = *(const float4*)&p.b_cls1[k];
      for (int c = 0; c < 8; ++c) {
        float4 v = *(const float4*)&p.partH[(size_t)c * 65536 + r * 1024 + k];
        s.x += v.x; s.y += v.y; s.z += v.z; s.w += v.w;
      }
      return make_float4(fmaxf(s.x, 0.f), fmaxf(s.y, 0.f), fmaxf(s.z, 0.f), fmaxf(s.w, 0.f));
    };
    auto Wl = [&](int k, int j) -> float4 {
      float v[4];
      #pragma unroll
      for (int i = 0; i < 4; ++i) { int jj = j + i; v[i] = (jj < NA) ? p.W_cls2[(size_t)k * NA + jj] : 0.f; }
      return make_float4(v[0], v[1], v[2], v[3]);
    };
    for (int job = blockIdx.x; job < 32; job += NB)
      gemm_job(lds, 0, job, 32, 1024, Al, Wl, p.partL, 64);
    gsync(bar);
  }
  // CL3: final reduce -> logits
  {
    int idx = blockIdx.x * NT + tid;
    if (idx < B * NA) {
      int r = idx / NA, j = idx - r * NA;
      float s = p.b_cls2[j];
      for (int c = 0; c < 32; ++c) s += p.partL[(size_t)c * 4096 + r * 64 + j];
      p.logits[idx] = s;
    }
  }
}

// ---- init: state + barrier ----
__global__ void pre_kernel(float* c_lstm, float* c_ctrl, float* att_stack, float* mem,
                           float* sptr, int* bar) {
  int idx = blockIdx.x * 256 + threadIdx.x;
  if (idx < B * DH) { c_lstm[idx] = 0.f; c_ctrl[idx] = 0.f; }
  if (idx < B * NN * LL) att_stack[idx] = 0.f;
  if (idx < B * DV) mem[idx] = 0.f;
  if (idx < B * LL) sptr[idx] = ((idx & (LL - 1)) == 0) ? 1.f : 0.f;
  if (idx < 64) bar[idx] = 0;
}

extern "C" void kernel_launch(void* const* d_in, const int* in_sizes, int n_in,
                              void* d_out, int out_size, void* d_ws, size_t ws_size,
                              hipStream_t stream) {
  KP p;
  p.questions = (const int*)d_in[0];
  p.qlen      = (const int*)d_in[1];
  p.conn      = (const float*)d_in[2];
  p.cat_mat   = (const int*)d_in[3];
  p.v_idx     = (const int*)d_in[4];
  p.attr_emb  = (const float*)d_in[5];
  p.edge_cat  = (const float*)d_in[6];
  p.enc_emb   = (const float*)d_in[7];
  p.Wx        = (const float*)d_in[8];
  p.Wh        = (const float*)d_in[9];
  p.b_lstm    = (const float*)d_in[10];
  p.W_cq      = (const float*)d_in[11];
  p.b_cq      = (const float*)d_in[12];
  p.W_mod     = (const float*)d_in[13];
  p.W_att     = (const float*)d_in[14];
  p.W_q       = (const float*)d_in[15];
  p.b_q       = (const float*)d_in[16];
  p.W_find    = (const float*)d_in[17];
  p.W_desc    = (const float*)d_in[18];
  p.W_cls1    = (const float*)d_in[19];
  p.b_cls1    = (const float*)d_in[20];
  p.W_cls2    = (const float*)d_in[21];
  p.b_cls2    = (const float*)d_in[22];
  p.logits    = (float*)d_out;

  float* w = (float*)d_ws;
  size_t off = 0;
  p.outs      = w + off; off += (size_t)S * B * DH;    // 2,097,152
  p.share     = w + off; off += 2457600;               // partLSTM/A/B/C/D union
  p.partE     = w + off; off += 262144;
  p.partH     = w + off; off += 524288;
  p.partL     = w + off; off += 131072;
  p.c_ctrl    = w + off; off += B * DH;
  p.c_lstm    = w + off; off += B * DH;
  p.uwe       = w + off; off += B * 528;
  p.we        = w + off; off += B * NE;
  p.mp        = w + off; off += B * MM;
  p.spv       = w + off; off += B * 12;
  p.ain       = w + off; off += B * NN;
  p.aw4       = w + off; off += B * NN;
  p.afind     = w + off; off += B * NN;
  p.atr       = w + off; off += B * NN;
  p.asum      = w + off; off += B;
  p.att_stack = w + off; off += B * NN * LL;
  p.sptr      = w + off; off += B * LL;
  p.mem       = w + off; off += B * DV;
  p.pooled    = w + off; off += B * DV;
  p.bar       = (int*)(w + off); off += 64;

  pre_kernel<<<256, 256, 0, stream>>>(p.c_lstm, p.c_ctrl, p.att_stack, p.mem, p.sptr, p.bar);

  void* args[] = { &p };
  hipError_t cerr = hipLaunchCooperativeKernel(reinterpret_cast<void*>(mega_kernel),
                                               dim3(NB), dim3(NT), args, 0, stream);
  if (cerr != hipSuccess) {
    (void)hipGetLastError();   // clear sticky error state
    // Fallback: plain launch. Co-residency of all 512 blocks is guaranteed by
    // __launch_bounds__(256,2) (<=256 VGPR, 16.6KB LDS -> 2 blocks/CU x 256 CU),
    // so the spin barrier remains safe.
    hipLaunchKernelGGL(mega_kernel, dim3(NB), dim3(NT), 0, stream, p);
  }
}